// Round 4
// baseline (170.851 us; speedup 1.0000x reference)
//
#include <hip/hip_runtime.h>

// Fused two-sided GraphSage-style embed + linear + dot. Single kernel.
// B=16384, MAX_DEG=50, D=64. Block = 512 threads (8 waves), EPB=16 elems,
// grid = 1024 (= 4 blocks/CU, 32 waves/CU).
// Phase 0: in-kernel mask-layout detection (wave 0, ballots).
// Phase 1: per-wave gather/aggregate for 2 elements; metadata for both
//          elements hoisted; 52 float4 gathers issued before reduces.
// Phase 2: mat-vec mini-GEMM, wave = (side, 4 elems), W amortized 4-16x.
// Phase 3: select + dot + wave reduce (counts kept in registers).

constexpr int KDEG   = 50;
constexpr int DIM    = 64;
constexpr int SLOTS  = 52;            // KDEG padded to multiple of 4
constexpr int ROUNDS = SLOTS / 4;     // 13
constexpr int EPB    = 16;            // elements per block

template <typename MT>
__device__ __forceinline__ void load_meta(const void* __restrict__ mask_p,
                                          const float* __restrict__ sel,
                                          const int* __restrict__ neibs,
                                          int base, int lane,
                                          int& idx, float& w, bool& act) {
  if (lane < KDEG) {
    MT m    = ((const MT*)mask_p)[base + lane];
    float s = sel[base + lane];
    idx     = neibs[base + lane];
    act     = (m != (MT)0);
    w       = act ? s : 0.0f;
  } else { idx = 0; w = 0.0f; act = false; }
}

// Compact active (idx,w) pairs into slots [0,cnt); fill [cnt,SLOTS) with zeros.
__device__ __forceinline__ int compact_side(int lane, int idx, float w, bool act,
                                            int* __restrict__ sidx,
                                            float* __restrict__ sw) {
  unsigned long long balA = __ballot(act);
  unsigned long long balI = __ballot(!act && (lane < SLOTS));
  int cnt = __popcll(balA);
  unsigned long long below = (1ULL << lane) - 1ULL;
  int pos = act ? __popcll(balA & below)
                : cnt + __popcll(balI & below);
  if (lane < SLOTS) {
    sidx[pos] = act ? idx : 0;
    sw[pos]   = act ? w   : 0.0f;
  }
  return cnt;
}

__device__ __forceinline__ float4 gather_rounds(const float* __restrict__ table,
                                                const int* __restrict__ sidx,
                                                const float* __restrict__ sw,
                                                int sub, int t) {
  float4 acc = make_float4(0.f, 0.f, 0.f, 0.f);
  #pragma unroll
  for (int r = 0; r < ROUNDS; ++r) {
    int   slot = r * 4 + sub;
    int   gi   = sidx[slot];              // LDS broadcast within 16-lane group
    float gw   = sw[slot];
    float4 v = ((const float4*)(table + (size_t)gi * DIM))[t];
    acc.x = fmaf(gw, v.x, acc.x);
    acc.y = fmaf(gw, v.y, acc.y);
    acc.z = fmaf(gw, v.z, acc.z);
    acc.w = fmaf(gw, v.w, acc.w);
  }
  return acc;
}

__device__ __forceinline__ void reduce_store(float4 agg_u, float4 agg_v,
                                             int cnt_u, int cnt_v,
                                             float* __restrict__ sxe,
                                             int sub, int t) {
  #pragma unroll
  for (int off = 16; off <= 32; off <<= 1) {
    agg_u.x += __shfl_xor(agg_u.x, off, 64);
    agg_u.y += __shfl_xor(agg_u.y, off, 64);
    agg_u.z += __shfl_xor(agg_u.z, off, 64);
    agg_u.w += __shfl_xor(agg_u.w, off, 64);
    agg_v.x += __shfl_xor(agg_v.x, off, 64);
    agg_v.y += __shfl_xor(agg_v.y, off, 64);
    agg_v.z += __shfl_xor(agg_v.z, off, 64);
    agg_v.w += __shfl_xor(agg_v.w, off, 64);
  }
  const float inv_u = 1.0f / fmaxf((float)cnt_u, 1.0f);
  const float inv_v = 1.0f / fmaxf((float)cnt_v, 1.0f);
  if (sub == 0) {   // lanes 0..15 hold the reduced agg
    float4 a = make_float4(agg_u.x * inv_u, agg_u.y * inv_u,
                           agg_u.z * inv_u, agg_u.w * inv_u);
    float4 b = make_float4(agg_v.x * inv_v, agg_v.y * inv_v,
                           agg_v.z * inv_v, agg_v.w * inv_v);
    ((float4*)(sxe + 64))[t]  = a;
    ((float4*)(sxe + 192))[t] = b;
  }
}

__global__ __launch_bounds__(512, 8) void fused_graphsage_dot(
    const int* __restrict__ nodes_u, const int* __restrict__ nodes_v,
    const int* __restrict__ u_neibs, const int* __restrict__ v_neibs,
    const void* __restrict__ u_mask_p, const void* __restrict__ v_mask_p,
    const float* __restrict__ u_sel, const float* __restrict__ v_sel,
    const float* __restrict__ u2e, const float* __restrict__ v2e,
    const float* __restrict__ Wu, const float* __restrict__ bu,
    const float* __restrict__ Wv, const float* __restrict__ bv,
    float* __restrict__ out)
{
  __shared__ float sx  [EPB][256];        // [self_u|agg_u|self_v|agg_v] per elem
  __shared__ float slin[2][EPB][DIM];     // mat-vec results per side
  __shared__ int   sidx[EPB][2][SLOTS];
  __shared__ float swt [EPB][2][SLOTS];
  __shared__ int   slay;

  const int lane = threadIdx.x & 63;
  const int wvid = threadIdx.x >> 6;      // 0..7
  const int sub  = lane >> 4, t = lane & 15;
  const int eb0  = blockIdx.x * EPB;
  const int e0   = wvid * 2, e1 = e0 + 1;
  const int g0   = eb0 + e0, g1 = eb0 + e1;
  const int b0   = g0 * KDEG, b1 = g1 * KDEG;

  // self-embedding loads issued first (independent of mask layout)
  float self_u0 = u2e[(size_t)nodes_u[g0] * DIM + lane];
  float self_v0 = v2e[(size_t)nodes_v[g0] * DIM + lane];
  float self_u1 = u2e[(size_t)nodes_u[g1] * DIM + lane];
  float self_v1 = v2e[(size_t)nodes_v[g1] * DIM + lane];

  // ---- Phase 0: mask storage layout detection (bool dtype ambiguity) ------
  // lay 0: int32 0/1   lay 1: uint8 0/1   lay 2: float32 0.0/1.0
  if (wvid == 0) {
    uchar4 b4 = ((const uchar4*)u_mask_p)[lane];   // first 256 bytes
    bool gt1  = (b4.x > 1) | (b4.y > 1) | (b4.z > 1) | (b4.w > 1);
    bool offw = ((b4.y | b4.z | b4.w) != 0);
    unsigned long long bg = __ballot(gt1);
    unsigned long long bo = __ballot(offw);
    if (lane == 0) slay = bg ? 2 : (bo ? 1 : 0);
  }
  __syncthreads();
  const int lay = slay;

  // ---- Phase 1: metadata (both elems) -> compact -> 52 gathers -> reduce ---
  int iu0, iv0, iu1, iv1; float wu0, wv0, wu1, wv1; bool au0, av0, au1, av1;
  if (lay == 0) {
    load_meta<int>(u_mask_p, u_sel, u_neibs, b0, lane, iu0, wu0, au0);
    load_meta<int>(v_mask_p, v_sel, v_neibs, b0, lane, iv0, wv0, av0);
    load_meta<int>(u_mask_p, u_sel, u_neibs, b1, lane, iu1, wu1, au1);
    load_meta<int>(v_mask_p, v_sel, v_neibs, b1, lane, iv1, wv1, av1);
  } else if (lay == 1) {
    load_meta<unsigned char>(u_mask_p, u_sel, u_neibs, b0, lane, iu0, wu0, au0);
    load_meta<unsigned char>(v_mask_p, v_sel, v_neibs, b0, lane, iv0, wv0, av0);
    load_meta<unsigned char>(u_mask_p, u_sel, u_neibs, b1, lane, iu1, wu1, au1);
    load_meta<unsigned char>(v_mask_p, v_sel, v_neibs, b1, lane, iv1, wv1, av1);
  } else {
    load_meta<float>(u_mask_p, u_sel, u_neibs, b0, lane, iu0, wu0, au0);
    load_meta<float>(v_mask_p, v_sel, v_neibs, b0, lane, iv0, wv0, av0);
    load_meta<float>(u_mask_p, u_sel, u_neibs, b1, lane, iu1, wu1, au1);
    load_meta<float>(v_mask_p, v_sel, v_neibs, b1, lane, iv1, wv1, av1);
  }
  int cnt_u0 = compact_side(lane, iu0, wu0, au0, sidx[e0][0], swt[e0][0]);
  int cnt_v0 = compact_side(lane, iv0, wv0, av0, sidx[e0][1], swt[e0][1]);
  int cnt_u1 = compact_side(lane, iu1, wu1, au1, sidx[e1][0], swt[e1][0]);
  int cnt_v1 = compact_side(lane, iv1, wv1, av1, sidx[e1][1], swt[e1][1]);

  sx[e0][lane]       = self_u0;
  sx[e0][128 + lane] = self_v0;
  sx[e1][lane]       = self_u1;
  sx[e1][128 + lane] = self_v1;

  // all 4 gather streams issued back-to-back (in-order issue -> max MLP),
  // reduces afterwards
  float4 agg_u0 = gather_rounds(u2e, sidx[e0][0], swt[e0][0], sub, t);
  float4 agg_v0 = gather_rounds(v2e, sidx[e0][1], swt[e0][1], sub, t);
  float4 agg_u1 = gather_rounds(u2e, sidx[e1][0], swt[e1][0], sub, t);
  float4 agg_v1 = gather_rounds(v2e, sidx[e1][1], swt[e1][1], sub, t);

  reduce_store(agg_u0, agg_v0, cnt_u0, cnt_v0, sx[e0], sub, t);
  reduce_store(agg_u1, agg_v1, cnt_u1, cnt_v1, sx[e1], sub, t);
  __syncthreads();

  // ---- Phase 2: mat-vec mini-GEMM ------------------------------------------
  // wave = (side, 4 elements), lane = output dim, k = 0..127
  {
    const int side = wvid & 1;
    const int eb   = (wvid >> 1) * 4;
    const float* __restrict__ W = side ? Wv : Wu;
    const float  bias = side ? bv[lane] : bu[lane];
    float a0 = bias, a1 = bias, a2 = bias, a3 = bias;
    const int xoff = side * 128;

    #pragma unroll 2
    for (int k4 = 0; k4 < 32; ++k4) {
      const int k = k4 * 4;
      float w0 = W[(k + 0) * DIM + lane];
      float w1 = W[(k + 1) * DIM + lane];
      float w2 = W[(k + 2) * DIM + lane];
      float w3 = W[(k + 3) * DIM + lane];
      float4 x0 = *(const float4*)&sx[eb + 0][xoff + k];
      float4 x1 = *(const float4*)&sx[eb + 1][xoff + k];
      float4 x2 = *(const float4*)&sx[eb + 2][xoff + k];
      float4 x3 = *(const float4*)&sx[eb + 3][xoff + k];
      a0 = fmaf(x0.x, w0, a0); a0 = fmaf(x0.y, w1, a0);
      a0 = fmaf(x0.z, w2, a0); a0 = fmaf(x0.w, w3, a0);
      a1 = fmaf(x1.x, w0, a1); a1 = fmaf(x1.y, w1, a1);
      a1 = fmaf(x1.z, w2, a1); a1 = fmaf(x1.w, w3, a1);
      a2 = fmaf(x2.x, w0, a2); a2 = fmaf(x2.y, w1, a2);
      a2 = fmaf(x2.z, w2, a2); a2 = fmaf(x2.w, w3, a2);
      a3 = fmaf(x3.x, w0, a3); a3 = fmaf(x3.y, w1, a3);
      a3 = fmaf(x3.z, w2, a3); a3 = fmaf(x3.w, w3, a3);
    }
    slin[side][eb + 0][lane] = a0;
    slin[side][eb + 1][lane] = a1;
    slin[side][eb + 2][lane] = a2;
    slin[side][eb + 3][lane] = a3;
  }
  __syncthreads();

  // ---- Phase 3: select + dot (counts still in registers) -------------------
  {
    float ue = (cnt_u0 > 0) ? slin[0][e0][lane] : sx[e0][lane];
    float ve = (cnt_v0 > 0) ? slin[1][e0][lane] : sx[e0][128 + lane];
    float p = ue * ve;
    #pragma unroll
    for (int off = 32; off > 0; off >>= 1) p += __shfl_xor(p, off, 64);
    if (lane == 0) out[g0] = p;
  }
  {
    float ue = (cnt_u1 > 0) ? slin[0][e1][lane] : sx[e1][lane];
    float ve = (cnt_v1 > 0) ? slin[1][e1][lane] : sx[e1][128 + lane];
    float p = ue * ve;
    #pragma unroll
    for (int off = 32; off > 0; off >>= 1) p += __shfl_xor(p, off, 64);
    if (lane == 0) out[g1] = p;
  }
}

extern "C" void kernel_launch(void* const* d_in, const int* in_sizes, int n_in,
                              void* d_out, int out_size, void* d_ws, size_t ws_size,
                              hipStream_t stream) {
  const int*   nodes_u = (const int*)  d_in[0];
  const int*   nodes_v = (const int*)  d_in[1];
  const int*   u_neibs = (const int*)  d_in[2];
  const int*   v_neibs = (const int*)  d_in[3];
  const void*  u_mask  =               d_in[4];
  const void*  v_mask  =               d_in[5];
  const float* u_sel   = (const float*)d_in[6];
  const float* v_sel   = (const float*)d_in[7];
  const float* u2e     = (const float*)d_in[8];
  const float* v2e     = (const float*)d_in[9];
  const float* Wu      = (const float*)d_in[10];
  const float* bu      = (const float*)d_in[11];
  const float* Wv      = (const float*)d_in[12];
  const float* bv      = (const float*)d_in[13];
  float* out = (float*)d_out;

  const int batch = in_sizes[0];           // 16384
  fused_graphsage_dot<<<batch / EPB, 512, 0, stream>>>(
      nodes_u, nodes_v, u_neibs, v_neibs, u_mask, v_mask, u_sel, v_sel,
      u2e, v2e, Wu, bu, Wv, bv, out);
}

// Round 5
// 56.180 us; speedup vs baseline: 3.0411x; 3.0411x over previous
//
#include <hip/hip_runtime.h>

// Fused two-sided GraphSage-style embed + linear + dot. Single kernel.
// B=16384, MAX_DEG=50, D=64. Block = 512 threads (8 waves), EPB=16 elems,
// grid = 1024 (4 blocks/CU, 32 waves/CU target).
// Phase 0: in-kernel mask-layout detection (wave 0, ballots).
// Phase 1: per-wave gather/aggregate, 2 elements SEQUENTIALLY (keeps register
//          pressure under the 64-VGPR cap; 26 float4 gathers in flight each).
// Phase 2: mat-vec mini-GEMM, wave = (side, 4 elems), W amortized, unroll 2.
// Phase 3: select + dot + wave reduce (counts kept in registers).

constexpr int KDEG   = 50;
constexpr int DIM    = 64;
constexpr int SLOTS  = 52;            // KDEG padded to multiple of 4
constexpr int ROUNDS = SLOTS / 4;     // 13
constexpr int EPB    = 16;            // elements per block

template <typename MT>
__device__ __forceinline__ void load_meta(const void* __restrict__ mask_p,
                                          const float* __restrict__ sel,
                                          const int* __restrict__ neibs,
                                          int base, int lane,
                                          int& idx, float& w, bool& act) {
  if (lane < KDEG) {
    MT m    = ((const MT*)mask_p)[base + lane];
    float s = sel[base + lane];
    idx     = neibs[base + lane];
    act     = (m != (MT)0);
    w       = act ? s : 0.0f;
  } else { idx = 0; w = 0.0f; act = false; }
}

// Compact active (idx,w) pairs into slots [0,cnt); fill [cnt,SLOTS) with zeros.
__device__ __forceinline__ int compact_side(int lane, int idx, float w, bool act,
                                            int* __restrict__ sidx,
                                            float* __restrict__ sw) {
  unsigned long long balA = __ballot(act);
  unsigned long long balI = __ballot(!act && (lane < SLOTS));
  int cnt = __popcll(balA);
  unsigned long long below = (1ULL << lane) - 1ULL;
  int pos = act ? __popcll(balA & below)
                : cnt + __popcll(balI & below);
  if (lane < SLOTS) {
    sidx[pos] = act ? idx : 0;
    sw[pos]   = act ? w   : 0.0f;
  }
  return cnt;
}

__device__ __forceinline__ float4 gather_rounds(const float* __restrict__ table,
                                                const int* __restrict__ sidx,
                                                const float* __restrict__ sw,
                                                int sub, int t) {
  float4 acc = make_float4(0.f, 0.f, 0.f, 0.f);
  #pragma unroll
  for (int r = 0; r < ROUNDS; ++r) {
    int   slot = r * 4 + sub;
    int   gi   = sidx[slot];              // LDS broadcast within 16-lane group
    float gw   = sw[slot];
    float4 v = ((const float4*)(table + (size_t)gi * DIM))[t];
    acc.x = fmaf(gw, v.x, acc.x);
    acc.y = fmaf(gw, v.y, acc.y);
    acc.z = fmaf(gw, v.z, acc.z);
    acc.w = fmaf(gw, v.w, acc.w);
  }
  return acc;
}

__global__ __launch_bounds__(512, 8) void fused_graphsage_dot(
    const int* __restrict__ nodes_u, const int* __restrict__ nodes_v,
    const int* __restrict__ u_neibs, const int* __restrict__ v_neibs,
    const void* __restrict__ u_mask_p, const void* __restrict__ v_mask_p,
    const float* __restrict__ u_sel, const float* __restrict__ v_sel,
    const float* __restrict__ u2e, const float* __restrict__ v2e,
    const float* __restrict__ Wu, const float* __restrict__ bu,
    const float* __restrict__ Wv, const float* __restrict__ bv,
    float* __restrict__ out)
{
  __shared__ float sx  [EPB][256];        // [self_u|agg_u|self_v|agg_v] per elem
  __shared__ float slin[2][EPB][DIM];     // mat-vec results per side
  __shared__ int   sidx[EPB][2][SLOTS];
  __shared__ float swt [EPB][2][SLOTS];
  __shared__ int   slay;

  const int lane = threadIdx.x & 63;
  const int wvid = threadIdx.x >> 6;      // 0..7
  const int sub  = lane >> 4, t = lane & 15;
  const int eb0  = blockIdx.x * EPB;

  // ---- Phase 0: mask storage layout detection (bool dtype ambiguity) ------
  // lay 0: int32 0/1   lay 1: uint8 0/1   lay 2: float32 0.0/1.0
  if (wvid == 0) {
    uchar4 b4 = ((const uchar4*)u_mask_p)[lane];   // first 256 bytes
    bool gt1  = (b4.x > 1) | (b4.y > 1) | (b4.z > 1) | (b4.w > 1);
    bool offw = ((b4.y | b4.z | b4.w) != 0);
    unsigned long long bg = __ballot(gt1);
    unsigned long long bo = __ballot(offw);
    if (lane == 0) slay = bg ? 2 : (bo ? 1 : 0);
  }
  __syncthreads();
  const int lay = slay;

  // ---- Phase 1: gather/aggregate, 2 elements per wave, SEQUENTIAL ----------
  int cntu[2], cntv[2];
  #pragma unroll
  for (int e2 = 0; e2 < 2; ++e2) {
    const int e    = wvid * 2 + e2;
    const int gi_  = eb0 + e;
    const int base = gi_ * KDEG;

    int iu, iv; float wu_, wv_; bool au, av;
    if (lay == 0) {
      load_meta<int>(u_mask_p, u_sel, u_neibs, base, lane, iu, wu_, au);
      load_meta<int>(v_mask_p, v_sel, v_neibs, base, lane, iv, wv_, av);
    } else if (lay == 1) {
      load_meta<unsigned char>(u_mask_p, u_sel, u_neibs, base, lane, iu, wu_, au);
      load_meta<unsigned char>(v_mask_p, v_sel, v_neibs, base, lane, iv, wv_, av);
    } else {
      load_meta<float>(u_mask_p, u_sel, u_neibs, base, lane, iu, wu_, au);
      load_meta<float>(v_mask_p, v_sel, v_neibs, base, lane, iv, wv_, av);
    }
    cntu[e2] = compact_side(lane, iu, wu_, au, sidx[e][0], swt[e][0]);
    cntv[e2] = compact_side(lane, iv, wv_, av, sidx[e][1], swt[e][1]);

    // self embeddings
    sx[e][lane]       = u2e[(size_t)nodes_u[gi_] * DIM + lane];
    sx[e][128 + lane] = v2e[(size_t)nodes_v[gi_] * DIM + lane];

    // gathers (sidx/swt written by this same wave -> no barrier needed)
    float4 agg_u = gather_rounds(u2e, sidx[e][0], swt[e][0], sub, t);
    float4 agg_v = gather_rounds(v2e, sidx[e][1], swt[e][1], sub, t);

    #pragma unroll
    for (int off = 16; off <= 32; off <<= 1) {
      agg_u.x += __shfl_xor(agg_u.x, off, 64);
      agg_u.y += __shfl_xor(agg_u.y, off, 64);
      agg_u.z += __shfl_xor(agg_u.z, off, 64);
      agg_u.w += __shfl_xor(agg_u.w, off, 64);
      agg_v.x += __shfl_xor(agg_v.x, off, 64);
      agg_v.y += __shfl_xor(agg_v.y, off, 64);
      agg_v.z += __shfl_xor(agg_v.z, off, 64);
      agg_v.w += __shfl_xor(agg_v.w, off, 64);
    }
    const float inv_u = 1.0f / fmaxf((float)cntu[e2], 1.0f);
    const float inv_v = 1.0f / fmaxf((float)cntv[e2], 1.0f);
    if (sub == 0) {   // lanes 0..15 hold the reduced agg
      float4 a = make_float4(agg_u.x * inv_u, agg_u.y * inv_u,
                             agg_u.z * inv_u, agg_u.w * inv_u);
      float4 b = make_float4(agg_v.x * inv_v, agg_v.y * inv_v,
                             agg_v.z * inv_v, agg_v.w * inv_v);
      ((float4*)&sx[e][64])[t]  = a;
      ((float4*)&sx[e][192])[t] = b;
    }
  }
  __syncthreads();

  // ---- Phase 2: mat-vec mini-GEMM ------------------------------------------
  // wave = (side, 4 elements), lane = output dim, k = 0..127
  {
    const int side = wvid & 1;
    const int eb   = (wvid >> 1) * 4;
    const float* __restrict__ W = side ? Wv : Wu;
    const float  bias = side ? bv[lane] : bu[lane];
    float a0 = bias, a1 = bias, a2 = bias, a3 = bias;
    const int xoff = side * 128;

    #pragma unroll 2
    for (int k4 = 0; k4 < 32; ++k4) {
      const int k = k4 * 4;
      float w0 = W[(k + 0) * DIM + lane];
      float w1 = W[(k + 1) * DIM + lane];
      float w2 = W[(k + 2) * DIM + lane];
      float w3 = W[(k + 3) * DIM + lane];
      float4 x0 = *(const float4*)&sx[eb + 0][xoff + k];
      float4 x1 = *(const float4*)&sx[eb + 1][xoff + k];
      float4 x2 = *(const float4*)&sx[eb + 2][xoff + k];
      float4 x3 = *(const float4*)&sx[eb + 3][xoff + k];
      a0 = fmaf(x0.x, w0, a0); a0 = fmaf(x0.y, w1, a0);
      a0 = fmaf(x0.z, w2, a0); a0 = fmaf(x0.w, w3, a0);
      a1 = fmaf(x1.x, w0, a1); a1 = fmaf(x1.y, w1, a1);
      a1 = fmaf(x1.z, w2, a1); a1 = fmaf(x1.w, w3, a1);
      a2 = fmaf(x2.x, w0, a2); a2 = fmaf(x2.y, w1, a2);
      a2 = fmaf(x2.z, w2, a2); a2 = fmaf(x2.w, w3, a2);
      a3 = fmaf(x3.x, w0, a3); a3 = fmaf(x3.y, w1, a3);
      a3 = fmaf(x3.z, w2, a3); a3 = fmaf(x3.w, w3, a3);
    }
    slin[side][eb + 0][lane] = a0;
    slin[side][eb + 1][lane] = a1;
    slin[side][eb + 2][lane] = a2;
    slin[side][eb + 3][lane] = a3;
  }
  __syncthreads();

  // ---- Phase 3: select + dot (counts still in registers) -------------------
  #pragma unroll
  for (int e2 = 0; e2 < 2; ++e2) {
    const int e = wvid * 2 + e2;
    float ue = (cntu[e2] > 0) ? slin[0][e][lane] : sx[e][lane];
    float ve = (cntv[e2] > 0) ? slin[1][e][lane] : sx[e][128 + lane];
    float p = ue * ve;
    #pragma unroll
    for (int off = 32; off > 0; off >>= 1) p += __shfl_xor(p, off, 64);
    if (lane == 0) out[eb0 + e] = p;
  }
}

extern "C" void kernel_launch(void* const* d_in, const int* in_sizes, int n_in,
                              void* d_out, int out_size, void* d_ws, size_t ws_size,
                              hipStream_t stream) {
  const int*   nodes_u = (const int*)  d_in[0];
  const int*   nodes_v = (const int*)  d_in[1];
  const int*   u_neibs = (const int*)  d_in[2];
  const int*   v_neibs = (const int*)  d_in[3];
  const void*  u_mask  =               d_in[4];
  const void*  v_mask  =               d_in[5];
  const float* u_sel   = (const float*)d_in[6];
  const float* v_sel   = (const float*)d_in[7];
  const float* u2e     = (const float*)d_in[8];
  const float* v2e     = (const float*)d_in[9];
  const float* Wu      = (const float*)d_in[10];
  const float* bu      = (const float*)d_in[11];
  const float* Wv      = (const float*)d_in[12];
  const float* bv      = (const float*)d_in[13];
  float* out = (float*)d_out;

  const int batch = in_sizes[0];           // 16384
  fused_graphsage_dot<<<batch / EPB, 512, 0, stream>>>(
      nodes_u, nodes_v, u_neibs, v_neibs, u_mask, v_mask, u_sel, v_sel,
      u2e, v2e, Wu, bu, Wv, bv, out);
}

// Round 6
// 53.870 us; speedup vs baseline: 3.1715x; 1.0429x over previous
//
#include <hip/hip_runtime.h>

// Fused two-sided GraphSage-style embed + linear + dot. Single kernel.
// B=16384, MAX_DEG=50, D=64. Block = 512 threads (8 waves), EPB=16 elems,
// grid = 1024 (4 blocks/CU, 32 waves/CU).
// Phase 0: in-kernel mask-layout detection (wave 0, ballots).
// Phase 1: lane = embedding dim. Per wave: hoist metadata for both elements,
//          compact (idx,w) into LDS int2 slots, then ONE interleaved gather
//          loop over all 4 (elem,side) streams: scalar row-loads (1 VGPR per
//          in-flight row), 16 rows in flight, scalar per-lane accumulators —
//          no cross-lane reduce needed.
// Phase 2: mat-vec mini-GEMM, wave = (side, 4 elems), W amortized, unroll 2.
// Phase 3: select + dot + wave reduce.

constexpr int KDEG  = 50;
constexpr int DIM   = 64;
constexpr int SLOTS = 56;             // KDEG padded to multiple of 8
constexpr int EPB   = 16;             // elements per block

template <typename MT>
__device__ __forceinline__ void load_meta(const void* __restrict__ mask_p,
                                          const float* __restrict__ sel,
                                          const int* __restrict__ neibs,
                                          int base, int lane,
                                          int& idx, float& w, bool& act) {
  if (lane < KDEG) {
    MT m    = ((const MT*)mask_p)[base + lane];
    float s = sel[base + lane];
    idx     = neibs[base + lane];
    act     = (m != (MT)0);
    w       = act ? s : 0.0f;
  } else { idx = 0; w = 0.0f; act = false; }
}

// Compact active (idx,w) pairs into slots [0,cnt); fill [cnt,SLOTS) with zeros.
__device__ __forceinline__ int compact_side(int lane, int idx, float w, bool act,
                                            int2* __restrict__ spair) {
  unsigned long long balA = __ballot(act);
  unsigned long long balI = __ballot(!act && (lane < SLOTS));
  int cnt = __popcll(balA);
  unsigned long long below = (1ULL << lane) - 1ULL;
  int pos = act ? __popcll(balA & below)
                : cnt + __popcll(balI & below);
  if (lane < SLOTS) {
    spair[pos] = make_int2(act ? idx : 0, act ? __float_as_int(w) : 0);
  }
  return cnt;
}

__global__ __launch_bounds__(512, 8) void fused_graphsage_dot(
    const int* __restrict__ nodes_u, const int* __restrict__ nodes_v,
    const int* __restrict__ u_neibs, const int* __restrict__ v_neibs,
    const void* __restrict__ u_mask_p, const void* __restrict__ v_mask_p,
    const float* __restrict__ u_sel, const float* __restrict__ v_sel,
    const float* __restrict__ u2e, const float* __restrict__ v2e,
    const float* __restrict__ Wu, const float* __restrict__ bu,
    const float* __restrict__ Wv, const float* __restrict__ bv,
    float* __restrict__ out)
{
  __shared__ float sx  [EPB][256];      // [self_u|agg_u|self_v|agg_v] per elem
  __shared__ float slin[2][EPB][DIM];   // mat-vec results per side
  __shared__ int2  spair[EPB][2][SLOTS];
  __shared__ int   slay;

  const int lane = threadIdx.x & 63;    // = embedding dim in phase 1
  const int wvid = threadIdx.x >> 6;    // 0..7
  const int eb0  = blockIdx.x * EPB;
  const int e0   = wvid * 2, e1 = e0 + 1;
  const int g0   = eb0 + e0, g1 = eb0 + e1;
  const int b0   = g0 * KDEG, b1 = g1 * KDEG;

  // self-embedding loads issued first (independent of everything below)
  float self_u0 = u2e[(size_t)nodes_u[g0] * DIM + lane];
  float self_v0 = v2e[(size_t)nodes_v[g0] * DIM + lane];
  float self_u1 = u2e[(size_t)nodes_u[g1] * DIM + lane];
  float self_v1 = v2e[(size_t)nodes_v[g1] * DIM + lane];

  // ---- Phase 0: mask storage layout detection (bool dtype ambiguity) ------
  // lay 0: int32 0/1   lay 1: uint8 0/1   lay 2: float32 0.0/1.0
  if (wvid == 0) {
    uchar4 b4 = ((const uchar4*)u_mask_p)[lane];   // first 256 bytes
    bool gt1  = (b4.x > 1) | (b4.y > 1) | (b4.z > 1) | (b4.w > 1);
    bool offw = ((b4.y | b4.z | b4.w) != 0);
    unsigned long long bg = __ballot(gt1);
    unsigned long long bo = __ballot(offw);
    if (lane == 0) slay = bg ? 2 : (bo ? 1 : 0);
  }
  __syncthreads();
  const int lay = slay;

  // ---- Phase 1a: metadata for BOTH elements, then compact ------------------
  int iu0, iv0, iu1, iv1; float wu0, wv0, wu1, wv1; bool au0_, av0_, au1_, av1_;
  if (lay == 0) {
    load_meta<int>(u_mask_p, u_sel, u_neibs, b0, lane, iu0, wu0, au0_);
    load_meta<int>(v_mask_p, v_sel, v_neibs, b0, lane, iv0, wv0, av0_);
    load_meta<int>(u_mask_p, u_sel, u_neibs, b1, lane, iu1, wu1, au1_);
    load_meta<int>(v_mask_p, v_sel, v_neibs, b1, lane, iv1, wv1, av1_);
  } else if (lay == 1) {
    load_meta<unsigned char>(u_mask_p, u_sel, u_neibs, b0, lane, iu0, wu0, au0_);
    load_meta<unsigned char>(v_mask_p, v_sel, v_neibs, b0, lane, iv0, wv0, av0_);
    load_meta<unsigned char>(u_mask_p, u_sel, u_neibs, b1, lane, iu1, wu1, au1_);
    load_meta<unsigned char>(v_mask_p, v_sel, v_neibs, b1, lane, iv1, wv1, av1_);
  } else {
    load_meta<float>(u_mask_p, u_sel, u_neibs, b0, lane, iu0, wu0, au0_);
    load_meta<float>(v_mask_p, v_sel, v_neibs, b0, lane, iv0, wv0, av0_);
    load_meta<float>(u_mask_p, u_sel, u_neibs, b1, lane, iu1, wu1, au1_);
    load_meta<float>(v_mask_p, v_sel, v_neibs, b1, lane, iv1, wv1, av1_);
  }
  const int cnt_u0 = compact_side(lane, iu0, wu0, au0_, spair[e0][0]);
  const int cnt_v0 = compact_side(lane, iv0, wv0, av0_, spair[e0][1]);
  const int cnt_u1 = compact_side(lane, iu1, wu1, au1_, spair[e1][0]);
  const int cnt_v1 = compact_side(lane, iv1, wv1, av1_, spair[e1][1]);

  // ---- Phase 1b: interleaved scalar-row gathers (4 streams, 16 in flight) --
  float accu0 = 0.f, accv0 = 0.f, accu1 = 0.f, accv1 = 0.f;
  {
    const int2* __restrict__ pU0 = spair[e0][0];
    const int2* __restrict__ pV0 = spair[e0][1];
    const int2* __restrict__ pU1 = spair[e1][0];
    const int2* __restrict__ pV1 = spair[e1][1];
    int cmax = max(max(cnt_u0, cnt_v0), max(cnt_u1, cnt_v1));
    int cm4  = (cmax + 3) & ~3;         // tail slots hold (0, 0.0f)
    for (int s = 0; s < cm4; s += 4) {
      #pragma unroll
      for (int j = 0; j < 4; ++j) {
        const int t = s + j;
        int2 a = pU0[t];                 // ds_read_b64, wave-uniform broadcast
        int2 b = pV0[t];
        int2 c = pU1[t];
        int2 d = pV1[t];
        accu0 = fmaf(__int_as_float(a.y), u2e[(size_t)a.x * DIM + lane], accu0);
        accv0 = fmaf(__int_as_float(b.y), v2e[(size_t)b.x * DIM + lane], accv0);
        accu1 = fmaf(__int_as_float(c.y), u2e[(size_t)c.x * DIM + lane], accu1);
        accv1 = fmaf(__int_as_float(d.y), v2e[(size_t)d.x * DIM + lane], accv1);
      }
    }
  }

  // ---- stage concat vectors (all 64 lanes, no cross-lane reduce needed) ----
  sx[e0][lane]       = self_u0;
  sx[e0][ 64 + lane] = accu0 * (1.0f / fmaxf((float)cnt_u0, 1.0f));
  sx[e0][128 + lane] = self_v0;
  sx[e0][192 + lane] = accv0 * (1.0f / fmaxf((float)cnt_v0, 1.0f));
  sx[e1][lane]       = self_u1;
  sx[e1][ 64 + lane] = accu1 * (1.0f / fmaxf((float)cnt_u1, 1.0f));
  sx[e1][128 + lane] = self_v1;
  sx[e1][192 + lane] = accv1 * (1.0f / fmaxf((float)cnt_v1, 1.0f));
  __syncthreads();

  // ---- Phase 2: mat-vec mini-GEMM ------------------------------------------
  // wave = (side, 4 elements), lane = output dim, k = 0..127
  {
    const int side = wvid & 1;
    const int eb   = (wvid >> 1) * 4;
    const float* __restrict__ W = side ? Wv : Wu;
    const float  bias = side ? bv[lane] : bu[lane];
    float a0 = bias, a1 = bias, a2 = bias, a3 = bias;
    const int xoff = side * 128;

    #pragma unroll 2
    for (int k4 = 0; k4 < 32; ++k4) {
      const int k = k4 * 4;
      float w0 = W[(k + 0) * DIM + lane];
      float w1 = W[(k + 1) * DIM + lane];
      float w2 = W[(k + 2) * DIM + lane];
      float w3 = W[(k + 3) * DIM + lane];
      float4 x0 = *(const float4*)&sx[eb + 0][xoff + k];
      float4 x1 = *(const float4*)&sx[eb + 1][xoff + k];
      float4 x2 = *(const float4*)&sx[eb + 2][xoff + k];
      float4 x3 = *(const float4*)&sx[eb + 3][xoff + k];
      a0 = fmaf(x0.x, w0, a0); a0 = fmaf(x0.y, w1, a0);
      a0 = fmaf(x0.z, w2, a0); a0 = fmaf(x0.w, w3, a0);
      a1 = fmaf(x1.x, w0, a1); a1 = fmaf(x1.y, w1, a1);
      a1 = fmaf(x1.z, w2, a1); a1 = fmaf(x1.w, w3, a1);
      a2 = fmaf(x2.x, w0, a2); a2 = fmaf(x2.y, w1, a2);
      a2 = fmaf(x2.z, w2, a2); a2 = fmaf(x2.w, w3, a2);
      a3 = fmaf(x3.x, w0, a3); a3 = fmaf(x3.y, w1, a3);
      a3 = fmaf(x3.z, w2, a3); a3 = fmaf(x3.w, w3, a3);
    }
    slin[side][eb + 0][lane] = a0;
    slin[side][eb + 1][lane] = a1;
    slin[side][eb + 2][lane] = a2;
    slin[side][eb + 3][lane] = a3;
  }
  __syncthreads();

  // ---- Phase 3: select + dot (counts still in registers) -------------------
  {
    float ue = (cnt_u0 > 0) ? slin[0][e0][lane] : sx[e0][lane];
    float ve = (cnt_v0 > 0) ? slin[1][e0][lane] : sx[e0][128 + lane];
    float p = ue * ve;
    #pragma unroll
    for (int off = 32; off > 0; off >>= 1) p += __shfl_xor(p, off, 64);
    if (lane == 0) out[g0] = p;
  }
  {
    float ue = (cnt_u1 > 0) ? slin[0][e1][lane] : sx[e1][lane];
    float ve = (cnt_v1 > 0) ? slin[1][e1][lane] : sx[e1][128 + lane];
    float p = ue * ve;
    #pragma unroll
    for (int off = 32; off > 0; off >>= 1) p += __shfl_xor(p, off, 64);
    if (lane == 0) out[g1] = p;
  }
}

extern "C" void kernel_launch(void* const* d_in, const int* in_sizes, int n_in,
                              void* d_out, int out_size, void* d_ws, size_t ws_size,
                              hipStream_t stream) {
  const int*   nodes_u = (const int*)  d_in[0];
  const int*   nodes_v = (const int*)  d_in[1];
  const int*   u_neibs = (const int*)  d_in[2];
  const int*   v_neibs = (const int*)  d_in[3];
  const void*  u_mask  =               d_in[4];
  const void*  v_mask  =               d_in[5];
  const float* u_sel   = (const float*)d_in[6];
  const float* v_sel   = (const float*)d_in[7];
  const float* u2e     = (const float*)d_in[8];
  const float* v2e     = (const float*)d_in[9];
  const float* Wu      = (const float*)d_in[10];
  const float* bu      = (const float*)d_in[11];
  const float* Wv      = (const float*)d_in[12];
  const float* bv      = (const float*)d_in[13];
  float* out = (float*)d_out;

  const int batch = in_sizes[0];           // 16384
  fused_graphsage_dot<<<batch / EPB, 512, 0, stream>>>(
      nodes_u, nodes_v, u_neibs, v_neibs, u_mask, v_mask, u_sel, v_sel,
      u2e, v2e, Wu, bu, Wv, bv, out);
}